// Round 1
// baseline (453.046 us; speedup 1.0000x reference)
//
#include <hip/hip_runtime.h>
#include <cstdint>

// ---------------------------------------------------------------------------
// ATSS post-processor: sigmoid scores -> exact per-image top-1000 (JAX tie
// order) -> box decode -> class-aware greedy NMS -> top-100 output.
//
// Problem constants (fixed by reference):
static constexpr int NI   = 8;          // images
static constexpr int CC   = 80;         // classes
static constexpr int HH   = 160;
static constexpr int WW   = 160;
static constexpr int LL   = HH * WW;    // 25600 locations
static constexpr int PRE_K  = 1000;
static constexpr int POST_K = 100;
static constexpr int CAP    = 32768;    // per-image candidate buffer capacity
static constexpr int HSIZE  = 2048;     // top-13-bit histogram buckets (score<1.0 -> bucket<2033)
static constexpr int BPI    = 100;      // hist/collect blocks per image (256 thr x 1 loc each)
static constexpr float PRE_T  = 0.05f;
static constexpr float NMS_T  = 0.6f;
static constexpr float CLIPV  = 4.135166556742356f;   // log(1000/16)
static constexpr float IMGM1  = 1279.0f;              // IMG_SIZE - 1

__device__ __forceinline__ float sigm(float x) { return 1.0f / (1.0f + expf(-x)); }

// ---------------------------------------------------------------------------
// K1: per-block histogram of candidate score bits (top 13 bits).
// Grid: NI*BPI blocks x 256 threads; thread t handles location lbase+t.
__global__ __launch_bounds__(256) void k_hist(const float* __restrict__ cls,
                                              const float* __restrict__ ctr,
                                              uint32_t* __restrict__ blockhist) {
    __shared__ uint32_t h[HSIZE];
    const int t = threadIdx.x;
    for (int i = t; i < HSIZE; i += 256) h[i] = 0u;
    __syncthreads();
    const int blk = blockIdx.x;
    const int n = blk / BPI;
    const int l = (blk % BPI) * 256 + t;
    const float cv = sigm(ctr[n * LL + l]);
    const float* cb = cls + ((size_t)n * CC) * LL + l;
    for (int c = 0; c < CC; ++c) {
        float p = sigm(cb[(size_t)c * LL]);
        if (p > PRE_T) {
            uint32_t b = __float_as_uint(p * cv) >> 19;   // score in (0,1) -> b < 2048
            atomicAdd(&h[b], 1u);
        }
    }
    __syncthreads();
    uint32_t* dst = blockhist + (size_t)blk * HSIZE;
    for (int i = t; i < HSIZE; i += 256) dst[i] = h[i];
}

// ---------------------------------------------------------------------------
// K2: per-image: reduce partial histograms, find highest bucket T with
// suffix-count >= PRE_K (== bucket of the 1000th-ranked candidate).
__global__ __launch_bounds__(256) void k_thresh(const uint32_t* __restrict__ blockhist,
                                                uint32_t* __restrict__ thresh) {
    __shared__ uint32_t h[HSIZE];
    __shared__ uint32_t chunk[256];
    const int n = blockIdx.x, t = threadIdx.x;
    for (int b = t; b < HSIZE; b += 256) {
        uint32_t s = 0;
        const uint32_t* src = blockhist + (size_t)(n * BPI) * HSIZE + b;
        for (int p = 0; p < BPI; ++p) s += src[(size_t)p * HSIZE];
        h[b] = s;
    }
    __syncthreads();
    uint32_t s = 0;
    for (int k = 0; k < 8; ++k) s += h[t * 8 + k];
    chunk[t] = s;
    __syncthreads();
    if (t == 0) {
        uint32_t cum = 0;
        int T = 0;
        for (int c = 255; c >= 0; --c) {
            if (cum + chunk[c] >= (uint32_t)PRE_K) {
                for (int b = c * 8 + 7; b >= c * 8; --b) {
                    cum += h[b];
                    if (cum >= (uint32_t)PRE_K) { T = b; break; }
                }
                break;
            }
            cum += chunk[c];
        }
        thresh[n] = ((uint32_t)T) << 19;   // lower bound bits of bucket T
    }
}

// ---------------------------------------------------------------------------
// K3: compact all candidates with score_bits >= per-image threshold into
// 64-bit keys: (score_bits << 32) | ~flat_idx  (value desc, index asc order).
__global__ __launch_bounds__(256) void k_collect(const float* __restrict__ cls,
                                                 const float* __restrict__ ctr,
                                                 const uint32_t* __restrict__ thresh,
                                                 uint32_t* __restrict__ cnt,
                                                 unsigned long long* __restrict__ cand) {
    const int t = threadIdx.x;
    const int blk = blockIdx.x;
    const int n = blk / BPI;
    const int l = (blk % BPI) * 256 + t;
    const uint32_t th = thresh[n];
    const float cv = sigm(ctr[n * LL + l]);
    const float* cb = cls + ((size_t)n * CC) * LL + l;
    for (int c = 0; c < CC; ++c) {
        float p = sigm(cb[(size_t)c * LL]);
        if (p > PRE_T) {
            uint32_t bits = __float_as_uint(p * cv);
            if (bits >= th) {
                uint32_t pos = atomicAdd(&cnt[n], 1u);
                if (pos < (uint32_t)CAP) {
                    uint32_t idx = (uint32_t)l * CC + (uint32_t)c;
                    cand[(size_t)n * CAP + pos] =
                        ((unsigned long long)bits << 32) | (uint32_t)(~idx);
                }
            }
        }
    }
}

// ---------------------------------------------------------------------------
// K4: per image, exact sorted top-1024 keys via iterated bitonic sort:
// keep running top-1024 in buf[0..1023], stream tiles into buf[1024..2047],
// full 2048-wide descending bitonic sort each tile.
__global__ __launch_bounds__(1024) void k_select(const unsigned long long* __restrict__ cand,
                                                 const uint32_t* __restrict__ cnt,
                                                 unsigned long long* __restrict__ topkeys) {
    __shared__ unsigned long long buf[2048];
    const int n = blockIdx.x, t = threadIdx.x;
    uint32_t M = cnt[n];
    if (M > (uint32_t)CAP) M = CAP;
    buf[t] = 0ULL;
    buf[t + 1024] = 0ULL;
    __syncthreads();
    const int tiles = (int)((M + 1023u) / 1024u);
    for (int tt = 0; tt < tiles; ++tt) {
        uint32_t gi = (uint32_t)tt * 1024u + (uint32_t)t;
        buf[1024 + t] = (gi < M) ? cand[(size_t)n * CAP + gi] : 0ULL;
        for (int k = 2; k <= 2048; k <<= 1) {
            for (int j = k >> 1; j > 0; j >>= 1) {
                __syncthreads();
                for (int i = t; i < 2048; i += 1024) {
                    int ixj = i ^ j;
                    if (ixj > i) {
                        unsigned long long a = buf[i], b = buf[ixj];
                        bool desc = ((i & k) == 0);
                        if (desc ? (a < b) : (a > b)) { buf[i] = b; buf[ixj] = a; }
                    }
                }
            }
        }
        __syncthreads();
    }
    topkeys[(size_t)n * 1024 + t] = buf[t];
}

// ---------------------------------------------------------------------------
// K5: decode + clip the top-1000 boxes, class-aware greedy NMS (early exit at
// 100 kept -- suppression only flows forward), write dets + labels.
__global__ __launch_bounds__(1024) void k_nms(const unsigned long long* __restrict__ topkeys,
                                              const float* __restrict__ reg,
                                              const float* __restrict__ anch,
                                              float* __restrict__ out) {
    __shared__ float bx0[PRE_K], bx1[PRE_K], bx2[PRE_K], bx3[PRE_K];
    __shared__ float ar[PRE_K], scv[PRE_K];
    __shared__ int clsA[PRE_K], sup[PRE_K];
    __shared__ int s_kept;
    __shared__ int s_list[POST_K];
    const int n = blockIdx.x, t = threadIdx.x;
    if (t == 0) s_kept = 0;
    if (t < PRE_K) {
        unsigned long long key = topkeys[(size_t)n * 1024 + t];
        if (key == 0ULL) {
            sup[t] = 2; clsA[t] = -1;
            bx0[t] = bx1[t] = bx2[t] = bx3[t] = 0.0f; ar[t] = 0.0f; scv[t] = 0.0f;
        } else {
            uint32_t bits = (uint32_t)(key >> 32);
            uint32_t idx = ~(uint32_t)key;
            int l = (int)(idx / (uint32_t)CC);
            int c = (int)(idx % (uint32_t)CC);
            float a0 = anch[l * 4 + 0], a1 = anch[l * 4 + 1];
            float a2 = anch[l * 4 + 2], a3 = anch[l * 4 + 3];
            float r0 = reg[((size_t)n * 4 + 0) * LL + l];
            float r1 = reg[((size_t)n * 4 + 1) * LL + l];
            float r2 = reg[((size_t)n * 4 + 2) * LL + l];
            float r3 = reg[((size_t)n * 4 + 3) * LL + l];
            float w  = a2 - a0 + 1.0f;
            float h  = a3 - a1 + 1.0f;
            float cx = a0 + 0.5f * w;
            float cy = a1 + 0.5f * h;
            float dx = r0 / 10.0f, dy = r1 / 10.0f;
            float dw = fminf(r2 / 5.0f, CLIPV), dh = fminf(r3 / 5.0f, CLIPV);
            float pcx = dx * w + cx, pcy = dy * h + cy;
            float pw = expf(dw) * w, ph = expf(dh) * h;
            float x1 = pcx - 0.5f * (pw - 1.0f);
            float y1 = pcy - 0.5f * (ph - 1.0f);
            float x2 = pcx + 0.5f * (pw - 1.0f);
            float y2 = pcy + 0.5f * (ph - 1.0f);
            x1 = fminf(fmaxf(x1, 0.0f), IMGM1);
            y1 = fminf(fmaxf(y1, 0.0f), IMGM1);
            x2 = fminf(fmaxf(x2, 0.0f), IMGM1);
            y2 = fminf(fmaxf(y2, 0.0f), IMGM1);
            bx0[t] = x1; bx1[t] = y1; bx2[t] = x2; bx3[t] = y2;
            ar[t] = fmaxf(x2 - x1, 0.0f) * fmaxf(y2 - y1, 0.0f);
            clsA[t] = c + 1;
            scv[t] = sqrtf(__uint_as_float(bits));
            sup[t] = 0;
        }
    }
    __syncthreads();
    // Greedy NMS in score order; first-100-kept is exact under early exit.
    for (int i = 0; i < PRE_K; ++i) {
        if (s_kept >= POST_K) break;          // uniform (read post-sync)
        if (sup[i] == 0) {
            if (t == 0) s_list[s_kept] = i;
            if (t > i && t < PRE_K && sup[t] == 0 && clsA[t] == clsA[i]) {
                float xx1 = fmaxf(bx0[i], bx0[t]);
                float yy1 = fmaxf(bx1[i], bx1[t]);
                float xx2 = fminf(bx2[i], bx2[t]);
                float yy2 = fminf(bx3[i], bx3[t]);
                float iw = fmaxf(xx2 - xx1, 0.0f);
                float ih = fmaxf(yy2 - yy1, 0.0f);
                float inter = iw * ih;
                float iou = inter / (ar[i] + ar[t] - inter + 1e-9f);
                if (iou > NMS_T) sup[t] = 1;
            }
            if (t == 0) s_kept = s_kept + 1;
        }
        __syncthreads();
    }
    __syncthreads();
    if (t < POST_K) {
        float o0 = 0.f, o1 = 0.f, o2 = 0.f, o3 = 0.f, o4 = 0.f, lab = 0.f;
        if (t < s_kept) {
            int i = s_list[t];
            o0 = bx0[i]; o1 = bx1[i]; o2 = bx2[i]; o3 = bx3[i];
            o4 = scv[i]; lab = (float)clsA[i];
        }
        float* dets = out + (size_t)(n * POST_K + t) * 5;
        dets[0] = o0; dets[1] = o1; dets[2] = o2; dets[3] = o3; dets[4] = o4;
        out[(size_t)NI * POST_K * 5 + (size_t)n * POST_K + t] = lab;
    }
}

// ---------------------------------------------------------------------------
extern "C" void kernel_launch(void* const* d_in, const int* in_sizes, int n_in,
                              void* d_out, int out_size, void* d_ws, size_t ws_size,
                              hipStream_t stream) {
    const float* reg  = (const float*)d_in[0];   // [8,4,160,160]
    const float* ctr  = (const float*)d_in[1];   // [8,1,160,160]
    const float* cls  = (const float*)d_in[2];   // [8,80,160,160]
    const float* anch = (const float*)d_in[3];   // [25600,4]
    float* out = (float*)d_out;                  // 8*100*5 dets, then 8*100 labels (as f32)

    // Workspace layout (all regions fully written before read each call):
    char* ws = (char*)d_ws;
    unsigned long long* cand = (unsigned long long*)ws;                 // 8*32768*8   = 2,097,152
    size_t off = (size_t)NI * CAP * 8;
    uint32_t* bh = (uint32_t*)(ws + off);                               // 800*2048*4  = 6,553,600
    off += (size_t)NI * BPI * HSIZE * 4;
    uint32_t* thr = (uint32_t*)(ws + off);                              // 8*4
    off += 32;
    uint32_t* cnt = (uint32_t*)(ws + off);                              // 8*4
    off += 32;
    unsigned long long* topk = (unsigned long long*)(ws + off);         // 8*1024*8

    hipMemsetAsync(cnt, 0, NI * sizeof(uint32_t), stream);
    k_hist   <<<NI * BPI, 256, 0, stream>>>(cls, ctr, bh);
    k_thresh <<<NI,       256, 0, stream>>>(bh, thr);
    k_collect<<<NI * BPI, 256, 0, stream>>>(cls, ctr, thr, cnt, cand);
    k_select <<<NI,      1024, 0, stream>>>(cand, cnt, topk);
    k_nms    <<<NI,      1024, 0, stream>>>(topk, reg, anch, out);
}

// Round 2
// 402.087 us; speedup vs baseline: 1.1267x; 1.1267x over previous
//
#include <hip/hip_runtime.h>
#include <cstdint>

// ---------------------------------------------------------------------------
// ATSS post-processor v2: vectorized two-pass exact top-1000 selection
// (histogram threshold -> compact -> bitonic sort) + greedy class-aware NMS.
//
static constexpr int NI   = 8;
static constexpr int CC   = 80;
static constexpr int HH   = 160;
static constexpr int WW   = 160;
static constexpr int LL   = HH * WW;     // 25600
static constexpr int PRE_K  = 1000;
static constexpr int POST_K = 100;
static constexpr int CAP    = 32768;     // per-image candidate capacity
static constexpr int HSIZE  = 2048;      // top-13-bit score histogram
static constexpr int CPCH   = 16;        // classes per chunk
static constexpr int NCH    = 5;         // 5 chunks * 16 = 80 classes
static constexpr int LPB    = 1024;      // locations per block (256 thr * float4)
static constexpr int LBLK   = 25;        // 25600 / 1024
static constexpr int BPI2   = NCH * LBLK;  // 125 blocks per image
static constexpr float PRE_T = 0.05f;
static constexpr float NMS_T = 0.6f;
static constexpr float CLIPV = 4.135166556742356f;   // log(1000/16)
static constexpr float IMGM1 = 1279.0f;

__device__ __forceinline__ float sigm(float x) { return 1.0f / (1.0f + expf(-x)); }

// ---------------------------------------------------------------------------
// K1: per-image global histogram of candidate score bits (top 13 bits).
// Grid: NI * BPI2 blocks x 256 thr. Thread: 4 consecutive locations (float4),
// 16 classes unrolled -> 16 outstanding 16B loads. 4-way wave-replicated LDS
// histogram, flushed with global atomics into ghist[n][2048].
__global__ __launch_bounds__(256) void k_hist(const float* __restrict__ cls,
                                              const float* __restrict__ ctr,
                                              uint32_t* __restrict__ ghist) {
    __shared__ uint32_t h[4][HSIZE];
    const int t = threadIdx.x;
    for (int i = t; i < 4 * HSIZE; i += 256) (&h[0][0])[i] = 0u;
    __syncthreads();
    const int blk = blockIdx.x;
    const int n = blk / BPI2, rem = blk % BPI2, ch = rem / LBLK, lb = rem % LBLK;
    const int l0 = lb * LPB + t * 4;
    const float4 cr = *(const float4*)&ctr[(size_t)n * LL + l0];
    float cv[4] = { sigm(cr.x), sigm(cr.y), sigm(cr.z), sigm(cr.w) };
    uint32_t* hw = h[t >> 6];
    const float* base = cls + ((size_t)n * CC + ch * CPCH) * LL + l0;
#pragma unroll
    for (int cc = 0; cc < CPCH; ++cc) {
        float4 x = *(const float4*)&base[(size_t)cc * LL];
        float p[4] = { sigm(x.x), sigm(x.y), sigm(x.z), sigm(x.w) };
#pragma unroll
        for (int k = 0; k < 4; ++k) {
            if (p[k] > PRE_T)
                atomicAdd(&hw[__float_as_uint(p[k] * cv[k]) >> 19], 1u);
        }
    }
    __syncthreads();
    for (int b = t; b < HSIZE; b += 256) {
        uint32_t s = h[0][b] + h[1][b] + h[2][b] + h[3][b];
        if (s) atomicAdd(&ghist[n * HSIZE + b], s);
    }
}

// ---------------------------------------------------------------------------
// K2: per image find highest bucket T with suffix-count >= PRE_K.
__global__ __launch_bounds__(256) void k_thresh(const uint32_t* __restrict__ ghist,
                                                uint32_t* __restrict__ thresh) {
    __shared__ uint32_t h[HSIZE];
    __shared__ uint32_t chunk[256];
    const int n = blockIdx.x, t = threadIdx.x;
    for (int b = t; b < HSIZE; b += 256) h[b] = ghist[n * HSIZE + b];
    __syncthreads();
    uint32_t s = 0;
    for (int k = 0; k < 8; ++k) s += h[t * 8 + k];
    chunk[t] = s;
    __syncthreads();
    if (t == 0) {
        uint32_t cum = 0;
        int T = 0;
        for (int c = 255; c >= 0; --c) {
            if (cum + chunk[c] >= (uint32_t)PRE_K) {
                for (int b = c * 8 + 7; b >= c * 8; --b) {
                    cum += h[b];
                    if (cum >= (uint32_t)PRE_K) { T = b; break; }
                }
                break;
            }
            cum += chunk[c];
        }
        thresh[n] = ((uint32_t)T) << 19;
    }
}

// ---------------------------------------------------------------------------
// K3: compact candidates >= threshold into keys (score_bits<<32 | ~flat_idx).
__global__ __launch_bounds__(256) void k_collect(const float* __restrict__ cls,
                                                 const float* __restrict__ ctr,
                                                 const uint32_t* __restrict__ thresh,
                                                 uint32_t* __restrict__ cnt,
                                                 unsigned long long* __restrict__ cand) {
    const int t = threadIdx.x;
    const int blk = blockIdx.x;
    const int n = blk / BPI2, rem = blk % BPI2, ch = rem / LBLK, lb = rem % LBLK;
    const int l0 = lb * LPB + t * 4;
    const uint32_t th = thresh[n];
    const float4 cr = *(const float4*)&ctr[(size_t)n * LL + l0];
    float cv[4] = { sigm(cr.x), sigm(cr.y), sigm(cr.z), sigm(cr.w) };
    const float* base = cls + ((size_t)n * CC + ch * CPCH) * LL + l0;
#pragma unroll
    for (int cc = 0; cc < CPCH; ++cc) {
        float4 x = *(const float4*)&base[(size_t)cc * LL];
        float p[4] = { sigm(x.x), sigm(x.y), sigm(x.z), sigm(x.w) };
#pragma unroll
        for (int k = 0; k < 4; ++k) {
            if (p[k] > PRE_T) {
                uint32_t bits = __float_as_uint(p[k] * cv[k]);
                if (bits >= th) {
                    uint32_t pos = atomicAdd(&cnt[n], 1u);
                    if (pos < (uint32_t)CAP) {
                        uint32_t idx = (uint32_t)(l0 + k) * CC + (uint32_t)(ch * CPCH + cc);
                        cand[(size_t)n * CAP + pos] =
                            ((unsigned long long)bits << 32) | (uint32_t)(~idx);
                    }
                }
            }
        }
    }
}

// ---------------------------------------------------------------------------
// full descending bitonic sort of buf[0..2047] by a 1024-thread block.
__device__ __forceinline__ void sort2048(unsigned long long* buf, int t) {
    for (int k = 2; k <= 2048; k <<= 1) {
        for (int j = k >> 1; j > 0; j >>= 1) {
            __syncthreads();
#pragma unroll
            for (int u = 0; u < 2; ++u) {
                int i = t + u * 1024;
                int ixj = i ^ j;
                if (ixj > i) {
                    unsigned long long a = buf[i], b = buf[ixj];
                    bool desc = ((i & k) == 0);
                    if (desc ? (a < b) : (a > b)) { buf[i] = b; buf[ixj] = a; }
                }
            }
        }
    }
    __syncthreads();
}

// ---------------------------------------------------------------------------
// K4: sort top-2048 keys (usually M<=2048 -> single sort), decode boxes into
// SoA workspace arrays for the NMS kernel.
__global__ __launch_bounds__(1024) void k_select(const unsigned long long* __restrict__ cand,
                                                 const uint32_t* __restrict__ cnt,
                                                 const float* __restrict__ reg,
                                                 const float* __restrict__ anch,
                                                 float* __restrict__ X1, float* __restrict__ Y1,
                                                 float* __restrict__ X2, float* __restrict__ Y2,
                                                 float* __restrict__ AR, float* __restrict__ SC,
                                                 int* __restrict__ CL) {
    __shared__ unsigned long long buf[2048];
    const int n = blockIdx.x, t = threadIdx.x;
    uint32_t M = cnt[n];
    if (M > (uint32_t)CAP) M = CAP;
    buf[t]        = ((uint32_t)t < M)          ? cand[(size_t)n * CAP + t]        : 0ULL;
    buf[1024 + t] = ((uint32_t)(1024 + t) < M) ? cand[(size_t)n * CAP + 1024 + t] : 0ULL;
    sort2048(buf, t);
    for (uint32_t s = 2048; s < M; s += 1024) {   // rare overflow path
        buf[1024 + t] = (s + t < M) ? cand[(size_t)n * CAP + s + t] : 0ULL;
        sort2048(buf, t);
    }
    // decode epilogue
    const unsigned long long key = buf[t];
    const int gi = n * 1024 + t;
    if (key == 0ULL) {
        X1[gi] = 0.f; Y1[gi] = 0.f; X2[gi] = 0.f; Y2[gi] = 0.f;
        AR[gi] = 0.f; SC[gi] = 0.f; CL[gi] = 0;
    } else {
        uint32_t bits = (uint32_t)(key >> 32);
        uint32_t idx = ~(uint32_t)key;
        int l = (int)(idx / (uint32_t)CC);
        int c = (int)(idx % (uint32_t)CC);
        float4 a = *(const float4*)&anch[l * 4];
        float r0 = reg[((size_t)n * 4 + 0) * LL + l];
        float r1 = reg[((size_t)n * 4 + 1) * LL + l];
        float r2 = reg[((size_t)n * 4 + 2) * LL + l];
        float r3 = reg[((size_t)n * 4 + 3) * LL + l];
        float w  = a.z - a.x + 1.0f;
        float h  = a.w - a.y + 1.0f;
        float cx = a.x + 0.5f * w;
        float cy = a.y + 0.5f * h;
        float dx = r0 / 10.0f, dy = r1 / 10.0f;
        float dw = fminf(r2 / 5.0f, CLIPV), dh = fminf(r3 / 5.0f, CLIPV);
        float pcx = dx * w + cx, pcy = dy * h + cy;
        float pw = expf(dw) * w, ph = expf(dh) * h;
        float x1 = pcx - 0.5f * (pw - 1.0f);
        float y1 = pcy - 0.5f * (ph - 1.0f);
        float x2 = pcx + 0.5f * (pw - 1.0f);
        float y2 = pcy + 0.5f * (ph - 1.0f);
        x1 = fminf(fmaxf(x1, 0.0f), IMGM1);
        y1 = fminf(fmaxf(y1, 0.0f), IMGM1);
        x2 = fminf(fmaxf(x2, 0.0f), IMGM1);
        y2 = fminf(fmaxf(y2, 0.0f), IMGM1);
        X1[gi] = x1; Y1[gi] = y1; X2[gi] = x2; Y2[gi] = y2;
        AR[gi] = fmaxf(x2 - x1, 0.0f) * fmaxf(y2 - y1, 0.0f);
        SC[gi] = sqrtf(__uint_as_float(bits));
        CL[gi] = c + 1;
    }
}

// ---------------------------------------------------------------------------
// K5: greedy class-aware NMS (256 threads, 4 candidates each, early exit at
// 100 kept -- suppression only flows forward so this is exact) + output.
__global__ __launch_bounds__(256) void k_nms(const float* __restrict__ X1, const float* __restrict__ Y1,
                                             const float* __restrict__ X2, const float* __restrict__ Y2,
                                             const float* __restrict__ AR, const float* __restrict__ SC,
                                             const int* __restrict__ CL,
                                             float* __restrict__ out) {
    __shared__ float bx0[PRE_K], bx1[PRE_K], bx2[PRE_K], bx3[PRE_K];
    __shared__ float ar[PRE_K], scv[PRE_K];
    __shared__ int clsA[PRE_K], sup[PRE_K];
    __shared__ int s_kept;
    __shared__ int s_list[POST_K];
    const int n = blockIdx.x, t = threadIdx.x;
    if (t == 0) s_kept = 0;
    for (int i = t; i < PRE_K; i += 256) {
        const int gi = n * 1024 + i;
        bx0[i] = X1[gi]; bx1[i] = Y1[gi]; bx2[i] = X2[gi]; bx3[i] = Y2[gi];
        ar[i] = AR[gi]; scv[i] = SC[gi];
        int c = CL[gi];
        clsA[i] = c;
        sup[i] = (c == 0) ? 2 : 0;
    }
    __syncthreads();
    for (int i = 0; i < PRE_K; ++i) {
        if (s_kept >= POST_K) break;
        if (sup[i] == 0) {
            if (t == 0) s_list[s_kept] = i;
            const float bi0 = bx0[i], bi1 = bx1[i], bi2 = bx2[i], bi3 = bx3[i];
            const float ai = ar[i];
            const int ci = clsA[i];
#pragma unroll
            for (int u = 0; u < 4; ++u) {
                const int jj = t + u * 256;
                if (jj > i && jj < PRE_K && sup[jj] == 0 && clsA[jj] == ci) {
                    float xx1 = fmaxf(bi0, bx0[jj]);
                    float yy1 = fmaxf(bi1, bx1[jj]);
                    float xx2 = fminf(bi2, bx2[jj]);
                    float yy2 = fminf(bi3, bx3[jj]);
                    float iw = fmaxf(xx2 - xx1, 0.0f);
                    float ih = fmaxf(yy2 - yy1, 0.0f);
                    float inter = iw * ih;
                    float iou = inter / (ai + ar[jj] - inter + 1e-9f);
                    if (iou > NMS_T) sup[jj] = 1;
                }
            }
            if (t == 0) s_kept = s_kept + 1;
        }
        __syncthreads();
    }
    __syncthreads();
    if (t < POST_K) {
        float o0 = 0.f, o1 = 0.f, o2 = 0.f, o3 = 0.f, o4 = 0.f, lab = 0.f;
        if (t < s_kept) {
            int i = s_list[t];
            o0 = bx0[i]; o1 = bx1[i]; o2 = bx2[i]; o3 = bx3[i];
            o4 = scv[i]; lab = (float)clsA[i];
        }
        float* dets = out + (size_t)(n * POST_K + t) * 5;
        dets[0] = o0; dets[1] = o1; dets[2] = o2; dets[3] = o3; dets[4] = o4;
        out[(size_t)NI * POST_K * 5 + (size_t)n * POST_K + t] = lab;
    }
}

// ---------------------------------------------------------------------------
extern "C" void kernel_launch(void* const* d_in, const int* in_sizes, int n_in,
                              void* d_out, int out_size, void* d_ws, size_t ws_size,
                              hipStream_t stream) {
    const float* reg  = (const float*)d_in[0];
    const float* ctr  = (const float*)d_in[1];
    const float* cls  = (const float*)d_in[2];
    const float* anch = (const float*)d_in[3];
    float* out = (float*)d_out;

    char* ws = (char*)d_ws;
    unsigned long long* cand = (unsigned long long*)ws;            // 2 MB
    size_t off = (size_t)NI * CAP * 8;
    uint32_t* ghist = (uint32_t*)(ws + off);                       // 64 KB
    off += (size_t)NI * HSIZE * 4;
    uint32_t* cnt = (uint32_t*)(ws + off);                         // 32 B (contig with ghist)
    off += 32;
    uint32_t* thr = (uint32_t*)(ws + off);
    off += 32;
    float* X1 = (float*)(ws + off); off += NI * 1024 * 4;
    float* Y1 = (float*)(ws + off); off += NI * 1024 * 4;
    float* X2 = (float*)(ws + off); off += NI * 1024 * 4;
    float* Y2 = (float*)(ws + off); off += NI * 1024 * 4;
    float* AR = (float*)(ws + off); off += NI * 1024 * 4;
    float* SC = (float*)(ws + off); off += NI * 1024 * 4;
    int*   CL = (int*)(ws + off);   off += NI * 1024 * 4;

    // zero ghist + cnt in one shot (contiguous)
    hipMemsetAsync(ghist, 0, (size_t)NI * HSIZE * 4 + 32, stream);
    k_hist   <<<NI * BPI2, 256, 0, stream>>>(cls, ctr, ghist);
    k_thresh <<<NI,        256, 0, stream>>>(ghist, thr);
    k_collect<<<NI * BPI2, 256, 0, stream>>>(cls, ctr, thr, cnt, cand);
    k_select <<<NI,       1024, 0, stream>>>(cand, cnt, reg, anch, X1, Y1, X2, Y2, AR, SC, CL);
    k_nms    <<<NI,        256, 0, stream>>>(X1, Y1, X2, Y2, AR, SC, CL, out);
}